// Round 14
// baseline (104.092 us; speedup 1.0000x reference)
//
#include <hip/hip_runtime.h>
#include <math.h>

// Problem constants (fixed shapes from setup_inputs)
#define BI 128
#define BT 128
#define RR 36
#define WW 50
#define DD 256
#define EPSF 1e-6f
// exp((s-1)/0.05) = exp2(s*C1 + C0), C1 = 20*log2(e), C0 = -C1
#define EXP2_C1 28.85390081777927f
#define EXP2_C0 (-28.85390081777927f)

#define A_TILES 3        // ceil(36/16)
#define B_TILES 4        // ceil(50/16)
#define KSTEPS 8         // 256 / 32
#define A_SLOTS (BI * A_TILES * KSTEPS * 64)  // 196608 slots x 16B = 3 MiB
#define B_SLOTS (BT * B_TILES * KSTEPS * 64)  // 262144 slots x 16B = 4 MiB
// d_ws layout: [Ah | Bh] (f16 fragments) = 3+4 MiB = 7,340,032 bytes

#define CV_AT (BI * A_TILES)   // 384 A-tiles
#define CV_BT (BT * B_TILES)   // 512 B-tiles

typedef short     v8ss __attribute__((ext_vector_type(8)));
typedef _Float16  v8hf __attribute__((ext_vector_type(8)));
typedef float     v4f  __attribute__((ext_vector_type(4)));

// MFMA shim: tolerate either builtin operand type (v8 half or v8 short).
template <typename V>
__device__ __forceinline__ auto mfma_impl(V a, V b, v4f c, int)
    -> decltype(__builtin_amdgcn_mfma_f32_16x16x32_f16(a, b, c, 0, 0, 0)) {
    return __builtin_amdgcn_mfma_f32_16x16x32_f16(a, b, c, 0, 0, 0);
}
template <typename V>
__device__ __forceinline__ v4f mfma_impl(V a, V b, v4f c, long) {
    v8ss a2 = __builtin_bit_cast(v8ss, a);
    v8ss b2 = __builtin_bit_cast(v8ss, b);
    return __builtin_amdgcn_mfma_f32_16x16x32_f16(a2, b2, c, 0, 0, 0);
}
__device__ __forceinline__ v4f mfma_f16(v8hf a, v8hf b, v4f c) {
    return mfma_impl(a, b, c, 0);
}

__device__ __forceinline__ float fast_rcp(float x) {
    return __builtin_amdgcn_rcpf(x);
}
__device__ __forceinline__ float fast_exp2(float x) {
    return __builtin_amdgcn_exp2f(x);
}

// DPP row_ror-based sum over each aligned 16-lane group (all lanes get sum)
template <int N>
__device__ __forceinline__ float dpp_ror_add(float x) {
    int xi = __builtin_bit_cast(int, x);
    int yi = __builtin_amdgcn_update_dpp(xi, xi, 0x120 | N, 0xF, 0xF, false);
    return x + __builtin_bit_cast(float, yi);
}
__device__ __forceinline__ float dpp_sum16(float x) {
    x = dpp_ror_add<1>(x);
    x = dpp_ror_add<2>(x);
    x = dpp_ror_add<4>(x);
    x = dpp_ror_add<8>(x);
    return x;
}

// ---------------------------------------------------------------------------
// Kernel 1 (R9's proven version): one block per 16-row output tile.
// ---------------------------------------------------------------------------
__global__ __launch_bounds__(256) void convert_kernel(
    const float* __restrict__ imgs, const float* __restrict__ caps,
    v8ss* __restrict__ Ah_g, v8ss* __restrict__ Bh_g)
{
    __shared__ float raw[16][260];   // +4 pad: odd float4-stride, conflict-light
    __shared__ float invn[16];

    const int t = threadIdx.x;
    const int b = blockIdx.x;
    const bool isA = b < CV_AT;
    int grp, tile, nrows;
    const float* src;
    if (isA) {
        grp = b / A_TILES; tile = b - grp * A_TILES;
        src = imgs + (size_t)grp * RR * DD;
        nrows = RR;
    } else {
        int bb = b - CV_AT;
        grp = bb / B_TILES; tile = bb - grp * B_TILES;
        src = caps + (size_t)grp * WW * DD;
        nrows = WW;
    }
    const size_t tbase = isA ? (size_t)b * (KSTEPS * 64)
                             : (size_t)(b - CV_AT) * (KSTEPS * 64);
    const int r0 = tile << 4;

    for (int f = t; f < 1024; f += 256) {
        const int row = f >> 6, c4 = f & 63;
        float4 v = make_float4(0.f, 0.f, 0.f, 0.f);
        const int r = r0 + row;
        if (r < nrows) v = *(const float4*)(src + (size_t)r * DD + c4 * 4);
        *(float4*)&raw[row][c4 * 4] = v;
    }
    __syncthreads();

    {
        const int row = t >> 4, seg = t & 15;
        float ss = 0.f;
#pragma unroll
        for (int k = 0; k < 16; ++k) {
            float x = raw[row][k * 16 + seg];
            ss += x * x;
        }
        ss = dpp_sum16(ss);
        if (seg == 0) invn[row] = 1.0f / fmaxf(sqrtf(ss), 1e-8f);
    }
    __syncthreads();

    for (int u = t; u < KSTEPS * 64; u += 256) {
        const int ks = u >> 6, sl = u & 63;
        const int rr = sl & 15, kq = sl >> 4;
        const float inv = invn[rr];
        const float* p = &raw[rr][ks * 32 + kq * 8];
        float4 f0 = *(const float4*)p;
        float4 f1 = *(const float4*)(p + 4);
        float xs[8] = {f0.x, f0.y, f0.z, f0.w, f1.x, f1.y, f1.z, f1.w};
        v8hf h;
#pragma unroll
        for (int e = 0; e < 8; ++e) h[e] = (_Float16)(xs[e] * inv);  // RNE f16
        if (isA) Ah_g[tbase + (size_t)ks * 64 + sl] = __builtin_bit_cast(v8ss, h);
        else     Bh_g[tbase + (size_t)ks * 64 + sl] = __builtin_bit_cast(v8ss, h);
    }
}

// ---------------------------------------------------------------------------
// Static Sinkhorn + output (R12's proven body, factored out).
// C/D layout: col = lane&15, row = (lane>>4)*4 + reg.
// ---------------------------------------------------------------------------
template <int MA, int NA>
__device__ __forceinline__ void sinkhorn_out(
    const v4f (&acc)[MA][NA], const int nr, const int nc,
    const int lane, float* __restrict__ outp)
{
    const int cl = lane & 15;
    const int rq = (lane >> 4) << 2;
    const float inv_nr = 1.0f / (float)nr;
    const float inv_nc = 1.0f / (float)nc;

    float P0[MA][NA][4];
    float tot = 0.f;
#pragma unroll
    for (int m = 0; m < MA; ++m)
#pragma unroll
        for (int n = 0; n < NA; ++n)
#pragma unroll
            for (int q = 0; q < 4; ++q) {
                const int row = (m << 4) + rq + q;
                const int col = (n << 4) + cl;
                float pv = 0.f;
                if (row < nr && col < nc)
                    pv = fast_exp2(fmaf(acc[m][n][q], EXP2_C1, EXP2_C0));
                P0[m][n][q] = pv;
                tot += pv;
            }
    tot = dpp_sum16(tot);
    tot += __shfl_xor(tot, 16, 64);
    tot += __shfl_xor(tot, 32, 64);
    const float gsc = fast_rcp(tot + EPSF);

    float u[MA][4], v[NA];
#pragma unroll
    for (int m = 0; m < MA; ++m)
#pragma unroll
        for (int q = 0; q < 4; ++q) u[m][q] = gsc;
#pragma unroll
    for (int n = 0; n < NA; ++n) v[n] = 1.0f;

#pragma unroll
    for (int it = 0; it < 3; ++it) {
#pragma unroll
        for (int m = 0; m < MA; ++m)
#pragma unroll
            for (int q = 0; q < 4; ++q) {
                float d = 0.f;
#pragma unroll
                for (int n = 0; n < NA; ++n)
                    d = fmaf(P0[m][n][q], v[n], d);
                d = dpp_sum16(d);
                const float t = fmaf(u[m][q], d, EPSF);
                u[m][q] *= inv_nr * fast_rcp(t);
            }
#pragma unroll
        for (int n = 0; n < NA; ++n) {
            float e = 0.f;
#pragma unroll
            for (int m = 0; m < MA; ++m)
#pragma unroll
                for (int q = 0; q < 4; ++q)
                    e = fmaf(P0[m][n][q], u[m][q], e);
            e += __shfl_xor(e, 16, 64);
            e += __shfl_xor(e, 32, 64);
            const float t = fmaf(v[n], e, EPSF);
            v[n] *= inv_nc * fast_rcp(t);
        }
    }

    float osum = 0.f;
#pragma unroll
    for (int m = 0; m < MA; ++m)
#pragma unroll
        for (int n = 0; n < NA; ++n)
#pragma unroll
            for (int q = 0; q < 4; ++q)
                osum = fmaf(acc[m][n][q], P0[m][n][q] * u[m][q] * v[n], osum);
    osum = dpp_sum16(osum);
    osum += __shfl_xor(osum, 16, 64);
    osum += __shfl_xor(osum, 32, 64);
    if (lane == 0) *outp = osum;
}

// Single-pair body (R12 structure: double-buffered loads, static tiles).
template <int MA, int NA>
__device__ __forceinline__ void pair_single(
    const v8ss* __restrict__ Ah_b, const v8ss* __restrict__ Bh_b,
    const int nr, const int nc, const int lane, float* __restrict__ outp)
{
    v4f acc[MA][NA];
#pragma unroll
    for (int m = 0; m < MA; ++m)
#pragma unroll
        for (int n = 0; n < NA; ++n) acc[m][n] = (v4f){0.f, 0.f, 0.f, 0.f};

    v8hf ah[2][MA], bh[2][NA];
    auto load_stage = [&](int ks, int buf) {
#pragma unroll
        for (int m = 0; m < MA; ++m)
            ah[buf][m] = __builtin_bit_cast(v8hf, Ah_b[(m * KSTEPS + ks) * 64]);
#pragma unroll
        for (int n = 0; n < NA; ++n)
            bh[buf][n] = __builtin_bit_cast(v8hf, Bh_b[(n * KSTEPS + ks) * 64]);
    };

    load_stage(0, 0);
#pragma unroll
    for (int ks = 0; ks < KSTEPS; ++ks) {
        const int cur = ks & 1;
        if (ks + 1 < KSTEPS) load_stage(ks + 1, cur ^ 1);
#pragma unroll
        for (int n = 0; n < NA; ++n)
#pragma unroll
            for (int m = 0; m < MA; ++m)
                acc[m][n] = mfma_f16(ah[cur][m], bh[cur][n], acc[m][n]);
    }
    sinkhorn_out<MA, NA>(acc, nr, nc, lane, outp);
}

// Fused 2-pair body (R14): one K-loop, A loaded ONCE, serves both pairs.
// Only instantiated for NA0+NA1 <= 4 (so NA0,NA1 <= 3).
template <int MA, int NA0, int NA1>
__device__ __forceinline__ void pair_fused(
    const v8ss* __restrict__ Ah_b,
    const v8ss* __restrict__ B0_b, const v8ss* __restrict__ B1_b,
    const int nr, const int nc0, const int nc1, const int lane,
    float* __restrict__ o0, float* __restrict__ o1)
{
    v4f acc0[MA][NA0], acc1[MA][NA1];
#pragma unroll
    for (int m = 0; m < MA; ++m) {
#pragma unroll
        for (int n = 0; n < NA0; ++n) acc0[m][n] = (v4f){0.f, 0.f, 0.f, 0.f};
#pragma unroll
        for (int n = 0; n < NA1; ++n) acc1[m][n] = (v4f){0.f, 0.f, 0.f, 0.f};
    }

    v8hf ah[2][MA], b0[2][NA0], b1[2][NA1];
    auto load_stage = [&](int ks, int buf) {
#pragma unroll
        for (int m = 0; m < MA; ++m)
            ah[buf][m] = __builtin_bit_cast(v8hf, Ah_b[(m * KSTEPS + ks) * 64]);
#pragma unroll
        for (int n = 0; n < NA0; ++n)
            b0[buf][n] = __builtin_bit_cast(v8hf, B0_b[(n * KSTEPS + ks) * 64]);
#pragma unroll
        for (int n = 0; n < NA1; ++n)
            b1[buf][n] = __builtin_bit_cast(v8hf, B1_b[(n * KSTEPS + ks) * 64]);
    };

    load_stage(0, 0);
#pragma unroll
    for (int ks = 0; ks < KSTEPS; ++ks) {
        const int cur = ks & 1;
        if (ks + 1 < KSTEPS) load_stage(ks + 1, cur ^ 1);
#pragma unroll
        for (int n = 0; n < NA0; ++n)
#pragma unroll
            for (int m = 0; m < MA; ++m)
                acc0[m][n] = mfma_f16(ah[cur][m], b0[cur][n], acc0[m][n]);
#pragma unroll
        for (int n = 0; n < NA1; ++n)
#pragma unroll
            for (int m = 0; m < MA; ++m)
                acc1[m][n] = mfma_f16(ah[cur][m], b1[cur][n], acc1[m][n]);
    }
    sinkhorn_out<MA, NA0>(acc0, nr, nc0, lane, o0);
    sinkhorn_out<MA, NA1>(acc1, nr, nc1, lane, o1);
}

__device__ __forceinline__ void single_dispatch(
    const v8ss* __restrict__ Ah_b, const v8ss* __restrict__ Bh_b,
    const int nr, const int nc, const int lane, float* __restrict__ outp)
{
    const int Ma = (nr + 15) >> 4;              // 1..3
    const int Na = (nc + 15) >> 4;              // 1..4
    switch (((Ma - 1) << 2) | (Na - 1)) {
        case 0:  pair_single<1, 1>(Ah_b, Bh_b, nr, nc, lane, outp); break;
        case 1:  pair_single<1, 2>(Ah_b, Bh_b, nr, nc, lane, outp); break;
        case 2:  pair_single<1, 3>(Ah_b, Bh_b, nr, nc, lane, outp); break;
        case 3:  pair_single<1, 4>(Ah_b, Bh_b, nr, nc, lane, outp); break;
        case 4:  pair_single<2, 1>(Ah_b, Bh_b, nr, nc, lane, outp); break;
        case 5:  pair_single<2, 2>(Ah_b, Bh_b, nr, nc, lane, outp); break;
        case 6:  pair_single<2, 3>(Ah_b, Bh_b, nr, nc, lane, outp); break;
        case 7:  pair_single<2, 4>(Ah_b, Bh_b, nr, nc, lane, outp); break;
        case 8:  pair_single<3, 1>(Ah_b, Bh_b, nr, nc, lane, outp); break;
        case 9:  pair_single<3, 2>(Ah_b, Bh_b, nr, nc, lane, outp); break;
        case 10: pair_single<3, 3>(Ah_b, Bh_b, nr, nc, lane, outp); break;
        default: pair_single<3, 4>(Ah_b, Bh_b, nr, nc, lane, outp); break;
    }
}

// ---------------------------------------------------------------------------
// Kernel 2 (R14): ONE WAVE = ONE BLOCK = TWO PAIRS (same i, adjacent j).
// If Na0+Na1 <= 4 (~61% of waves): fused K-loop — A loaded once, per-kstep
// exposed latency amortized over both pairs. Else: two sequential single
// bodies (A L1-warm on the second). XCD swizzle as R9: xcd = blockIdx&7
// owns j-slice [16x,16x+16); consecutive blocks share i (A L2-hot).
// __launch_bounds__(64,4) = proven 128-VGPR class; worst live ~110 regs.
// ---------------------------------------------------------------------------
__global__ __launch_bounds__(64, 4) void pair_kernel(
    const v8ss* __restrict__ Ah_g, const v8ss* __restrict__ Bh_g,
    const int* __restrict__ img_lens, const int* __restrict__ cap_lens,
    float* __restrict__ out)
{
    const int lane = threadIdx.x;
    const int x    = blockIdx.x & 7;            // XCD id (round-robin)
    const int g    = blockIdx.x >> 3;           // within-XCD block index
    const int i    = g >> 3;                    // 8 blocks per i per XCD
    const int j0   = (x << 4) + ((g & 7) << 1); // two adjacent j per wave
    const int j1   = j0 + 1;

    const int nr  = img_lens[i];
    const int nc0 = cap_lens[j0];
    const int nc1 = cap_lens[j1];
    const int Ma  = (nr + 15) >> 4;             // 1..3
    const int Na0 = (nc0 + 15) >> 4;            // 1..4
    const int Na1 = (nc1 + 15) >> 4;            // 1..4

    const v8ss* Ah_b = Ah_g + (size_t)i * (A_TILES * KSTEPS * 64) + lane;
    const v8ss* B0_b = Bh_g + (size_t)j0 * (B_TILES * KSTEPS * 64) + lane;
    const v8ss* B1_b = Bh_g + (size_t)j1 * (B_TILES * KSTEPS * 64) + lane;
    float* o0 = out + i * BT + j0;
    float* o1 = out + i * BT + j1;

    if (Na0 + Na1 <= 4) {
        // NA0, NA1 in 1..3 here
        switch ((Ma - 1) * 9 + (Na0 - 1) * 3 + (Na1 - 1)) {
            case 0:  pair_fused<1, 1, 1>(Ah_b, B0_b, B1_b, nr, nc0, nc1, lane, o0, o1); break;
            case 1:  pair_fused<1, 1, 2>(Ah_b, B0_b, B1_b, nr, nc0, nc1, lane, o0, o1); break;
            case 2:  pair_fused<1, 1, 3>(Ah_b, B0_b, B1_b, nr, nc0, nc1, lane, o0, o1); break;
            case 3:  pair_fused<1, 2, 1>(Ah_b, B0_b, B1_b, nr, nc0, nc1, lane, o0, o1); break;
            case 4:  pair_fused<1, 2, 2>(Ah_b, B0_b, B1_b, nr, nc0, nc1, lane, o0, o1); break;
            case 6:  pair_fused<1, 3, 1>(Ah_b, B0_b, B1_b, nr, nc0, nc1, lane, o0, o1); break;
            case 9:  pair_fused<2, 1, 1>(Ah_b, B0_b, B1_b, nr, nc0, nc1, lane, o0, o1); break;
            case 10: pair_fused<2, 1, 2>(Ah_b, B0_b, B1_b, nr, nc0, nc1, lane, o0, o1); break;
            case 11: pair_fused<2, 1, 3>(Ah_b, B0_b, B1_b, nr, nc0, nc1, lane, o0, o1); break;
            case 12: pair_fused<2, 2, 1>(Ah_b, B0_b, B1_b, nr, nc0, nc1, lane, o0, o1); break;
            case 13: pair_fused<2, 2, 2>(Ah_b, B0_b, B1_b, nr, nc0, nc1, lane, o0, o1); break;
            case 15: pair_fused<2, 3, 1>(Ah_b, B0_b, B1_b, nr, nc0, nc1, lane, o0, o1); break;
            case 18: pair_fused<3, 1, 1>(Ah_b, B0_b, B1_b, nr, nc0, nc1, lane, o0, o1); break;
            case 19: pair_fused<3, 1, 2>(Ah_b, B0_b, B1_b, nr, nc0, nc1, lane, o0, o1); break;
            case 20: pair_fused<3, 1, 3>(Ah_b, B0_b, B1_b, nr, nc0, nc1, lane, o0, o1); break;
            case 21: pair_fused<3, 2, 1>(Ah_b, B0_b, B1_b, nr, nc0, nc1, lane, o0, o1); break;
            case 22: pair_fused<3, 2, 2>(Ah_b, B0_b, B1_b, nr, nc0, nc1, lane, o0, o1); break;
            case 24: pair_fused<3, 3, 1>(Ah_b, B0_b, B1_b, nr, nc0, nc1, lane, o0, o1); break;
            default: // unreachable combos: safe sequential fallback
                single_dispatch(Ah_b, B0_b, nr, nc0, lane, o0);
                single_dispatch(Ah_b, B1_b, nr, nc1, lane, o1);
                break;
        }
    } else {
        single_dispatch(Ah_b, B0_b, nr, nc0, lane, o0);
        single_dispatch(Ah_b, B1_b, nr, nc1, lane, o1);
    }
}

extern "C" void kernel_launch(void* const* d_in, const int* in_sizes, int n_in,
                              void* d_out, int out_size, void* d_ws, size_t ws_size,
                              hipStream_t stream) {
    const float* imgs     = (const float*)d_in[0];
    const float* caps     = (const float*)d_in[1];
    const int*   img_lens = (const int*)d_in[2];
    const int*   cap_lens = (const int*)d_in[3];
    float* out = (float*)d_out;

    // workspace layout (7,340,032 bytes used of d_ws)
    v8ss* Ah_g = (v8ss*)d_ws;
    v8ss* Bh_g = Ah_g + A_SLOTS;

    hipLaunchKernelGGL(convert_kernel, dim3(CV_AT + CV_BT), dim3(256), 0, stream,
                       imgs, caps, Ah_g, Bh_g);
    // 8192 blocks x 64 threads = 8192 waves x 2 pairs = 16384 pairs
    hipLaunchKernelGGL(pair_kernel, dim3(BI * BT / 2), dim3(64), 0, stream,
                       Ah_g, Bh_g, img_lens, cap_lens, out);
}

// Round 15
// 98.102 us; speedup vs baseline: 1.0611x; 1.0611x over previous
//
#include <hip/hip_runtime.h>
#include <math.h>

// Problem constants (fixed shapes from setup_inputs)
#define BI 128
#define BT 128
#define RR 36
#define WW 50
#define DD 256
#define EPSF 1e-6f
// exp((s-1)/0.05) = exp2(s*C1 + C0), C1 = 20*log2(e), C0 = -C1
#define EXP2_C1 28.85390081777927f
#define EXP2_C0 (-28.85390081777927f)

#define A_TILES 3        // ceil(36/16)
#define B_TILES 4        // ceil(50/16)
#define KSTEPS 8         // 256 / 32
#define A_SLOTS (BI * A_TILES * KSTEPS * 64)  // 196608 slots x 16B = 3 MiB
#define B_SLOTS (BT * B_TILES * KSTEPS * 64)  // 262144 slots x 16B = 4 MiB
// d_ws layout: [Ah | Bh] (f16 fragments) = 3+4 MiB = 7,340,032 bytes

#define CV_AT (BI * A_TILES)   // 384 A-tiles
#define CV_BT (BT * B_TILES)   // 512 B-tiles

typedef short     v8ss __attribute__((ext_vector_type(8)));
typedef _Float16  v8hf __attribute__((ext_vector_type(8)));
typedef float     v4f  __attribute__((ext_vector_type(4)));

// MFMA shim: tolerate either builtin operand type (v8 half or v8 short).
template <typename V>
__device__ __forceinline__ auto mfma_impl(V a, V b, v4f c, int)
    -> decltype(__builtin_amdgcn_mfma_f32_16x16x32_f16(a, b, c, 0, 0, 0)) {
    return __builtin_amdgcn_mfma_f32_16x16x32_f16(a, b, c, 0, 0, 0);
}
template <typename V>
__device__ __forceinline__ v4f mfma_impl(V a, V b, v4f c, long) {
    v8ss a2 = __builtin_bit_cast(v8ss, a);
    v8ss b2 = __builtin_bit_cast(v8ss, b);
    return __builtin_amdgcn_mfma_f32_16x16x32_f16(a2, b2, c, 0, 0, 0);
}
__device__ __forceinline__ v4f mfma_f16(v8hf a, v8hf b, v4f c) {
    return mfma_impl(a, b, c, 0);
}

__device__ __forceinline__ float fast_rcp(float x) {
    return __builtin_amdgcn_rcpf(x);
}
__device__ __forceinline__ float fast_exp2(float x) {
    return __builtin_amdgcn_exp2f(x);
}

// DPP row_ror-based sum over each aligned 16-lane group (all lanes get sum)
template <int N>
__device__ __forceinline__ float dpp_ror_add(float x) {
    int xi = __builtin_bit_cast(int, x);
    int yi = __builtin_amdgcn_update_dpp(xi, xi, 0x120 | N, 0xF, 0xF, false);
    return x + __builtin_bit_cast(float, yi);
}
__device__ __forceinline__ float dpp_sum16(float x) {
    x = dpp_ror_add<1>(x);
    x = dpp_ror_add<2>(x);
    x = dpp_ror_add<4>(x);
    x = dpp_ror_add<8>(x);
    return x;
}

// ---------------------------------------------------------------------------
// Kernel 1 (R9's proven version): one block per 16-row output tile.
//   step 1: coalesced load of 16 rows x 256 floats into LDS
//   step 2: per-row inverse L2 norms (16 lanes/row, DPP reduce)
//   step 3: f16 convert, COALESCED fragment stores.
// Pad rows write zeros so poisoned d_ws is fully initialized.
// ---------------------------------------------------------------------------
__global__ __launch_bounds__(256) void convert_kernel(
    const float* __restrict__ imgs, const float* __restrict__ caps,
    v8ss* __restrict__ Ah_g, v8ss* __restrict__ Bh_g)
{
    __shared__ float raw[16][260];   // +4 pad: odd float4-stride, conflict-light
    __shared__ float invn[16];

    const int t = threadIdx.x;
    const int b = blockIdx.x;
    const bool isA = b < CV_AT;
    int grp, tile, nrows;
    const float* src;
    if (isA) {
        grp = b / A_TILES; tile = b - grp * A_TILES;
        src = imgs + (size_t)grp * RR * DD;
        nrows = RR;
    } else {
        int bb = b - CV_AT;
        grp = bb / B_TILES; tile = bb - grp * B_TILES;
        src = caps + (size_t)grp * WW * DD;
        nrows = WW;
    }
    const size_t tbase = isA ? (size_t)b * (KSTEPS * 64)
                             : (size_t)(b - CV_AT) * (KSTEPS * 64);
    const int r0 = tile << 4;

    // step 1: stage (rows >= nrows -> zeros)
    for (int f = t; f < 1024; f += 256) {
        const int row = f >> 6, c4 = f & 63;
        float4 v = make_float4(0.f, 0.f, 0.f, 0.f);
        const int r = r0 + row;
        if (r < nrows) v = *(const float4*)(src + (size_t)r * DD + c4 * 4);
        *(float4*)&raw[row][c4 * 4] = v;
    }
    __syncthreads();

    // step 2: inverse norms; 16 lanes per row
    {
        const int row = t >> 4, seg = t & 15;
        float ss = 0.f;
#pragma unroll
        for (int k = 0; k < 16; ++k) {
            float x = raw[row][k * 16 + seg];
            ss += x * x;
        }
        ss = dpp_sum16(ss);
        if (seg == 0) invn[row] = 1.0f / fmaxf(sqrtf(ss), 1e-8f);
    }
    __syncthreads();

    // step 3: convert + coalesced stores (512 slots, 2 per thread)
    for (int u = t; u < KSTEPS * 64; u += 256) {
        const int ks = u >> 6, sl = u & 63;
        const int rr = sl & 15, kq = sl >> 4;
        const float inv = invn[rr];
        const float* p = &raw[rr][ks * 32 + kq * 8];
        float4 f0 = *(const float4*)p;
        float4 f1 = *(const float4*)(p + 4);
        float xs[8] = {f0.x, f0.y, f0.z, f0.w, f1.x, f1.y, f1.z, f1.w};
        v8hf h;
#pragma unroll
        for (int e = 0; e < 8; ++e) h[e] = (_Float16)(xs[e] * inv);  // RNE f16
        if (isA) Ah_g[tbase + (size_t)ks * 64 + sl] = __builtin_bit_cast(v8ss, h);
        else     Bh_g[tbase + (size_t)ks * 64 + sl] = __builtin_bit_cast(v8ss, h);
    }
}

// ---------------------------------------------------------------------------
// STATIC pair body, templated on active tile counts (MA in 1..3, NA in 1..4).
// R12: predicated `if (m<Ma)` pruning executed the full 3x4x4 Sinkhorn;
// static bodies execute active tiles only (~3x less VALU) — proven win.
// Double-buffered fragment loads, acc retained, u/v-factorized Sinkhorn,
// DPP row sums, xor-shfl col sums, v_rcp_f32, exp folded to fma+v_exp.
// C/D layout: col = lane&15, row = (lane>>4)*4 + reg.
// ---------------------------------------------------------------------------
template <int MA, int NA>
__device__ __forceinline__ void pair_body(
    const v8ss* __restrict__ Ah_b, const v8ss* __restrict__ Bh_b,
    const int nr, const int nc, const int lane, float* __restrict__ outp)
{
    v4f acc[MA][NA];
#pragma unroll
    for (int m = 0; m < MA; ++m)
#pragma unroll
        for (int n = 0; n < NA; ++n) acc[m][n] = (v4f){0.f, 0.f, 0.f, 0.f};

    v8hf ah[2][MA], bh[2][NA];
    auto load_stage = [&](int ks, int buf) {
#pragma unroll
        for (int m = 0; m < MA; ++m)
            ah[buf][m] = __builtin_bit_cast(v8hf, Ah_b[(m * KSTEPS + ks) * 64]);
#pragma unroll
        for (int n = 0; n < NA; ++n)
            bh[buf][n] = __builtin_bit_cast(v8hf, Bh_b[(n * KSTEPS + ks) * 64]);
    };

    load_stage(0, 0);
#pragma unroll
    for (int ks = 0; ks < KSTEPS; ++ks) {
        const int cur = ks & 1;
        if (ks + 1 < KSTEPS) load_stage(ks + 1, cur ^ 1);
#pragma unroll
        for (int n = 0; n < NA; ++n)
#pragma unroll
            for (int m = 0; m < MA; ++m)
                acc[m][n] = mfma_f16(ah[cur][m], bh[cur][n], acc[m][n]);
    }

    // ---- Sinkhorn via u/v factorization ----
    const int cl = lane & 15;
    const int rq = (lane >> 4) << 2;
    const float inv_nr = 1.0f / (float)nr;
    const float inv_nc = 1.0f / (float)nc;

    float P0[MA][NA][4];
    float tot = 0.f;
#pragma unroll
    for (int m = 0; m < MA; ++m)
#pragma unroll
        for (int n = 0; n < NA; ++n)
#pragma unroll
            for (int q = 0; q < 4; ++q) {
                const int row = (m << 4) + rq + q;
                const int col = (n << 4) + cl;
                float pv = 0.f;
                if (row < nr && col < nc)
                    pv = fast_exp2(fmaf(acc[m][n][q], EXP2_C1, EXP2_C0));
                P0[m][n][q] = pv;
                tot += pv;
            }
    tot = dpp_sum16(tot);
    tot += __shfl_xor(tot, 16, 64);
    tot += __shfl_xor(tot, 32, 64);
    const float gsc = fast_rcp(tot + EPSF);

    float u[MA][4], v[NA];
#pragma unroll
    for (int m = 0; m < MA; ++m)
#pragma unroll
        for (int q = 0; q < 4; ++q) u[m][q] = gsc;
#pragma unroll
    for (int n = 0; n < NA; ++n) v[n] = 1.0f;

#pragma unroll
    for (int it = 0; it < 3; ++it) {
        // row update: t = u[r]*sum_c(P0*v); u *= (1/nr)*rcp(t+EPS)
#pragma unroll
        for (int m = 0; m < MA; ++m)
#pragma unroll
            for (int q = 0; q < 4; ++q) {
                float d = 0.f;
#pragma unroll
                for (int n = 0; n < NA; ++n)
                    d = fmaf(P0[m][n][q], v[n], d);
                d = dpp_sum16(d);
                const float t = fmaf(u[m][q], d, EPSF);
                u[m][q] *= inv_nr * fast_rcp(t);
            }
        // col update: t = v[c]*sum_r(P0*u); v *= (1/nc)*rcp(t+EPS)
#pragma unroll
        for (int n = 0; n < NA; ++n) {
            float e = 0.f;
#pragma unroll
            for (int m = 0; m < MA; ++m)
#pragma unroll
                for (int q = 0; q < 4; ++q)
                    e = fmaf(P0[m][n][q], u[m][q], e);
            e += __shfl_xor(e, 16, 64);
            e += __shfl_xor(e, 32, 64);
            const float t = fmaf(v[n], e, EPSF);
            v[n] *= inv_nc * fast_rcp(t);
        }
    }

    // ---- output: sum(S * P0 * u * v) ----
    float osum = 0.f;
#pragma unroll
    for (int m = 0; m < MA; ++m)
#pragma unroll
        for (int n = 0; n < NA; ++n)
#pragma unroll
            for (int q = 0; q < 4; ++q)
                osum = fmaf(acc[m][n][q], P0[m][n][q] * u[m][q] * v[n], osum);
    osum = dpp_sum16(osum);
    osum += __shfl_xor(osum, 16, 64);
    osum += __shfl_xor(osum, 32, 64);
    if (lane == 0) *outp = osum;
}

__device__ __forceinline__ void pair_dispatch(
    const v8ss* __restrict__ Ah_b, const v8ss* __restrict__ Bh_b,
    const int nr, const int nc, const int lane, float* __restrict__ outp)
{
    const int Ma = (nr + 15) >> 4;              // 1..3
    const int Na = (nc + 15) >> 4;              // 1..4
    const int code = ((Ma - 1) << 2) | (Na - 1);
    switch (code) {
        case 0:  pair_body<1, 1>(Ah_b, Bh_b, nr, nc, lane, outp); break;
        case 1:  pair_body<1, 2>(Ah_b, Bh_b, nr, nc, lane, outp); break;
        case 2:  pair_body<1, 3>(Ah_b, Bh_b, nr, nc, lane, outp); break;
        case 3:  pair_body<1, 4>(Ah_b, Bh_b, nr, nc, lane, outp); break;
        case 4:  pair_body<2, 1>(Ah_b, Bh_b, nr, nc, lane, outp); break;
        case 5:  pair_body<2, 2>(Ah_b, Bh_b, nr, nc, lane, outp); break;
        case 6:  pair_body<2, 3>(Ah_b, Bh_b, nr, nc, lane, outp); break;
        case 7:  pair_body<2, 4>(Ah_b, Bh_b, nr, nc, lane, outp); break;
        case 8:  pair_body<3, 1>(Ah_b, Bh_b, nr, nc, lane, outp); break;
        case 9:  pair_body<3, 2>(Ah_b, Bh_b, nr, nc, lane, outp); break;
        case 10: pair_body<3, 3>(Ah_b, Bh_b, nr, nc, lane, outp); break;
        default: pair_body<3, 4>(Ah_b, Bh_b, nr, nc, lane, outp); break;
    }
}

// ---------------------------------------------------------------------------
// Kernel 2 (R13 = measured optimum): TWO INDEPENDENT PAIRS PER 128-THREAD
// BLOCK (same i, two adjacent j -> same Ma). Each wave runs ONE static
// single-pair body (no fusion — R14's fused bodies spilled 10 MB to scratch).
// __launch_bounds__(128,4) = 128-VGPR class (worst live ~112, no spill).
// XCD swizzle: xcd = blockIdx&7 owns j-slice [16x,16x+16); consecutive
// blocks share i (A L2-hot on every XCD).
// ---------------------------------------------------------------------------
__global__ __launch_bounds__(128, 4) void pair_kernel(
    const v8ss* __restrict__ Ah_g, const v8ss* __restrict__ Bh_g,
    const int* __restrict__ img_lens, const int* __restrict__ cap_lens,
    float* __restrict__ out)
{
    const int lane = threadIdx.x & 63;
    const int w    = threadIdx.x >> 6;          // 0..1
    const int x    = blockIdx.x & 7;            // XCD id (round-robin)
    const int g    = blockIdx.x >> 3;           // within-XCD block index
    const int i    = g >> 3;                    // 8 blocks per i per XCD
    const int j    = (x << 4) + ((g & 7) << 1) + w;  // two adjacent j per block

    const int nr = img_lens[i];
    const int nc = cap_lens[j];

    const v8ss* Ah_b = Ah_g + (size_t)i * (A_TILES * KSTEPS * 64) + lane;
    const v8ss* Bh_b = Bh_g + (size_t)j * (B_TILES * KSTEPS * 64) + lane;
    float* outp = out + i * BT + j;

    pair_dispatch(Ah_b, Bh_b, nr, nc, lane, outp);
}

extern "C" void kernel_launch(void* const* d_in, const int* in_sizes, int n_in,
                              void* d_out, int out_size, void* d_ws, size_t ws_size,
                              hipStream_t stream) {
    const float* imgs     = (const float*)d_in[0];
    const float* caps     = (const float*)d_in[1];
    const int*   img_lens = (const int*)d_in[2];
    const int*   cap_lens = (const int*)d_in[3];
    float* out = (float*)d_out;

    // workspace layout (7,340,032 bytes used of d_ws)
    v8ss* Ah_g = (v8ss*)d_ws;
    v8ss* Bh_g = Ah_g + A_SLOTS;

    hipLaunchKernelGGL(convert_kernel, dim3(CV_AT + CV_BT), dim3(256), 0, stream,
                       imgs, caps, Ah_g, Bh_g);
    // 8192 blocks x 128 threads = 16384 pairs (2 per block, same i)
    hipLaunchKernelGGL(pair_kernel, dim3(BI * BT / 2), dim3(128), 0, stream,
                       Ah_g, Bh_g, img_lens, cap_lens, out);
}